// Round 17
// baseline (10820.684 us; speedup 1.0000x reference)
//
#include <hip/hip_runtime.h>

// ---------------------------------------------------------------------------
// Persistent fused 2-layer LSTM + FC for MI355X — v15: v14 + h1 fragments
// direct-to-register for L1 waves (h1 leaves the serial stage chain).
//  Mechanism: the h1->h1 recurrence is the critical loop. v14 paid
//  h0-drain + retry + h1-drain + h1-repack + barrier + LDS-read before the
//  first h1 MFMA. v15: L1 waves issue their own h1-frag loads (64x u64,
//  linear ring offsets) at LOOP TOP, so h1's LLC RTT overlaps the whole
//  h0 drain+repack+barrier; post-barrier they verify/strip in-register
//  (payload() x4 per frag) and MFMA from regs. h0 keeps the staged path
//  (now 32KB, ONE drain). Safety: barrier+mutual coupling keeps skew<=1;
//  slot-overwrite safety follows the same store->verify dependency chain
//  as v13 (re-derived for the direct path).
// v13/v14 recap (4028/4026 us): pass-1-under-RTT repack, u64 paired
// stores (WRITE halved), 4-way MFMA chains (neutral, kept).
// Structure: 128 WGs x 256 thr (4 waves), 4 groups x 32 WGs, 1 WG/CU.
// wv0/wv1 = L0 (8 units, K=576), wv2/wv3 = L1 (8 units, K=1024). Weights
// resident. h: u32 = fp16|(tag<<16), 3-slot agent-scope ring, speculative
// read + per-word retry, 1 barrier/step.
// ---------------------------------------------------------------------------

#define H      512
#define T_SEQ  1024
#define DIN    64
#define STEPS  1025

#define SLOT_U32 16384           // [2 layers][16 batch][512 units] tagged u32
#define GRP_U32  49152           // 3 slots
#define WS_BYTES (4 * GRP_U32 * 4)

typedef _Float16 f16x8 __attribute__((ext_vector_type(8)));
typedef float    f32x4 __attribute__((ext_vector_type(4)));
typedef unsigned u32x4 __attribute__((ext_vector_type(4)));
typedef unsigned long long u64t;

__device__ __forceinline__ u64t ld_u64(const u64t* p) {
  return __hip_atomic_load((u64t*)p, __ATOMIC_RELAXED, __HIP_MEMORY_SCOPE_AGENT);
}
__device__ __forceinline__ void st_u64(u64t* p, u64t v) {
  __hip_atomic_store(p, v, __ATOMIC_RELAXED, __HIP_MEMORY_SCOPE_AGENT);
}
__device__ __forceinline__ f16x8 pk8(float4 a, float4 b) {
  f16x8 r;
  r[0] = (_Float16)a.x; r[1] = (_Float16)a.y; r[2] = (_Float16)a.z; r[3] = (_Float16)a.w;
  r[4] = (_Float16)b.x; r[5] = (_Float16)b.y; r[6] = (_Float16)b.z; r[7] = (_Float16)b.w;
  return r;
}
__device__ __forceinline__ f16x8 cvt8(const float* p) {
  return pk8(*(const float4*)p, *(const float4*)(p + 4));
}
__device__ __forceinline__ f32x4 mfma16(f16x8 a, f16x8 b, f32x4 c) {
  return __builtin_amdgcn_mfma_f32_16x16x32_f16(a, b, c, 0, 0, 0);
}
__device__ __forceinline__ float rcpf_(float x) {
#if __has_builtin(__builtin_amdgcn_rcpf)
  return __builtin_amdgcn_rcpf(x);
#else
  return 1.0f / x;
#endif
}
__device__ __forceinline__ float sigm(float x) {
  x = fminf(fmaxf(x, -30.f), 30.f);
  return rcpf_(1.f + __expf(-x));
}
__device__ __forceinline__ float tanhx(float x) {
  x = fminf(fmaxf(x, -15.f), 15.f);
  float e = __expf(2.f * x);
  return (e - 1.f) * rcpf_(e + 1.f);
}
__device__ __forceinline__ unsigned payload(u64t v) {
  return ((unsigned)v & 0xffffu) | ((unsigned)(v >> 32) << 16);
}

__global__ __launch_bounds__(256, 1)
void lstm_fused(const float* __restrict__ x,
                const float* __restrict__ Wih0, const float* __restrict__ Whh0,
                const float* __restrict__ bih0, const float* __restrict__ bhh0,
                const float* __restrict__ Wih1, const float* __restrict__ Whh1,
                const float* __restrict__ bih1, const float* __restrict__ bhh1,
                const float* __restrict__ fcw,  const float* __restrict__ fcb,
                float* __restrict__ out, unsigned* __restrict__ ws)
{
  // double-buffered staged h0 ONLY: [buf][16 batch][260 u32]
  __shared__ unsigned sH[2][4160];

  const int tid  = threadIdx.x;
  const int wid  = blockIdx.x;
  const int g    = wid >> 5;           // batch group 0..3
  const int w    = wid & 31;           // WG within group
  const int wv   = tid >> 6;           // wave 0..3
  const int lane = tid & 63;
  const int bcol = lane & 15;          // MFMA N col = batch-in-group
  const int kgrp = lane >> 4;
  const int layer = wv >> 1;
  const int hb    = w * 16 + (wv & 1) * 8;   // 8 units of this wave

  unsigned* gbase = ws + g * GRP_U32;

  // ---- resident weights: 2 M-tiles = even units (hb+2k) / odd (hb+2k+1)
  //      M rows gate-interleaved: row m -> gate m&3, unit hb + 2*(m>>2)(+1).
  const int src_m = lane & 15;
  const int gr0 = (src_m & 3) * H + hb + 2 * (src_m >> 2);  // even-unit row
  const int gr1 = gr0 + 1;                                  // odd-unit row
  f16x8 wA[2][32];
  if (layer == 0) {                    // K = 64(x) + 512(h0): frags 0..17
    #pragma unroll
    for (int f = 0; f < 18; ++f) {
      const float *p0, *p1;
      if (f < 2) {
        p0 = Wih0 + (size_t)gr0 * DIN + f * 32 + kgrp * 8;
        p1 = Wih0 + (size_t)gr1 * DIN + f * 32 + kgrp * 8;
      } else {
        p0 = Whh0 + (size_t)gr0 * H + (f - 2) * 32 + kgrp * 8;
        p1 = Whh0 + (size_t)gr1 * H + (f - 2) * 32 + kgrp * 8;
      }
      wA[0][f] = cvt8(p0); wA[1][f] = cvt8(p1);
    }
  } else {                             // K = 512(h0) + 512(h1): frags 0..31
    #pragma unroll
    for (int f = 0; f < 16; ++f) {
      int col = f * 32 + kgrp * 8;
      wA[0][f] = cvt8(Wih1 + (size_t)gr0 * H + col);
      wA[1][f] = cvt8(Wih1 + (size_t)gr1 * H + col);
    }
    #pragma unroll
    for (int f = 16; f < 32; ++f) {
      int col = (f - 16) * 32 + kgrp * 8;
      wA[0][f] = cvt8(Whh1 + (size_t)gr0 * H + col);
      wA[1][f] = cvt8(Whh1 + (size_t)gr1 * H + col);
    }
  }
  float bias[2][4];
  {
    const float* bi = layer ? bih1 : bih0;
    const float* bh = layer ? bhh1 : bhh0;
    const int u0 = hb + 2 * kgrp, u1 = u0 + 1;
    #pragma unroll
    for (int rr = 0; rr < 4; ++rr) {
      bias[0][rr] = bi[rr * H + u0] + bh[rr * H + u0];
      bias[1][rr] = bi[rr * H + u1] + bh[rr * H + u1];
    }
  }

  // zero both staging buffers once (step 0 reads zeros as h_{-1})
  for (int i = tid; i < 2 * 4160; i += 256) ((unsigned*)sH)[i] = 0;
  __syncthreads();

  float cst0 = 0.f, cst1 = 0.f;
  unsigned spins = 0;                  // cumulative guard (normal use ~1e5)
  const int rowb = bcol * 1040 + kgrp * 16;   // byte offset of B-frag row
  // h1 direct-read base u64 offset for this lane (frag f, quad q):
  //   bcol*256 + f*16 + kgrp*4 + q   within the slot's h1 region
  const int h1base = bcol * 256 + kgrp * 4;

  for (int s = 0; s < STEPS; ++s) {
    const u64t* slot = (const u64t*)(gbase + ((s > 0 ? s - 1 : 0) % 3) * SLOT_U32);
    // ---- L1: issue h1-frag loads FIRST (critical recurrence; RTT overlaps
    //      the entire h0 drain+repack+barrier below)
    u64t hr[64];
    if (layer == 1 && s > 0) {
      const u64t* s1 = slot + 4096;              // h1 region (u64 index)
      #pragma unroll
      for (int e = 0; e < 64; ++e)
        hr[e] = ld_u64(s1 + h1base + (e >> 2) * 16 + (e & 3));
    }
    // x prefetch for L0 waves (frags 0,1)
    float4 xr0 = {0,0,0,0}, xr1 = xr0, xr2 = xr0, xr3 = xr0;
    if (layer == 0) {
      int t = (s < T_SEQ) ? s : (T_SEQ - 1);
      const float* xp = x + ((size_t)((g * 16 + bcol) * T_SEQ + t)) * DIN + kgrp * 8;
      xr0 = *(const float4*)xp;        xr1 = *(const float4*)(xp + 4);
      xr2 = *(const float4*)(xp + 32); xr3 = *(const float4*)(xp + 36);
    }
    // ---- stage h0 (32KB, ONE 16-u64 drain) into buf s&1
    if (s > 0) {
      const unsigned want = (unsigned)s;
      unsigned* dstbuf = sH[s & 1];
      u64t v0[16];
      #pragma unroll
      for (int i = 0; i < 16; ++i) v0[i] = ld_u64(slot + tid + i * 256);
      for (;;) {
        unsigned bad = 0;
        #pragma unroll
        for (int i = 0; i < 16; ++i) {
          unsigned lo = (unsigned)v0[i], hi = (unsigned)(v0[i] >> 32);
          if (((lo >> 16) ^ want) | ((hi >> 16) ^ want)) bad |= (1u << i);
        }
        if (!bad) break;
        if (++spins > 8000000u) break;           // bounded anti-hang guard
        #pragma unroll
        for (int i = 0; i < 16; ++i)
          if (bad & (1u << i)) v0[i] = ld_u64(slot + tid + i * 256);
      }
      #pragma unroll
      for (int i = 0; i < 16; ++i) {             // repack h0 -> LDS
        int j = tid + i * 256;                   // [16][256] u64 index
        dstbuf[(j >> 8) * 260 + (j & 255)] = payload(v0[i]);
      }
    }
    __syncthreads();                             // h0 staged; WAR via dbuf

    const bool act = layer ? (s > 0) : (s < T_SEQ);
    float hv0 = 0.f, hv1 = 0.f;
    if (act) {
      f32x4 a0e = {0,0,0,0}, a0o = {0,0,0,0};
      f32x4 a1e = {0,0,0,0}, a1o = {0,0,0,0};
      const char* cur = (const char*)sH[s & 1];
      if (layer == 0) {
        f16x8 b0 = pk8(xr0, xr1);
        a0e = mfma16(wA[0][0], b0, a0e); a1e = mfma16(wA[1][0], b0, a1e);
        f16x8 b1 = pk8(xr2, xr3);
        a0o = mfma16(wA[0][1], b1, a0o); a1o = mfma16(wA[1][1], b1, a1o);
        #pragma unroll
        for (int f = 2; f < 18; ++f) {
          f16x8 bf = *(const f16x8*)(cur + rowb + (f - 2) * 64);
          if (f & 1) { a0o = mfma16(wA[0][f], bf, a0o); a1o = mfma16(wA[1][f], bf, a1o); }
          else       { a0e = mfma16(wA[0][f], bf, a0e); a1e = mfma16(wA[1][f], bf, a1e); }
        }
      } else {
        // verify h1 direct reads (usually already arrived), per-word retry
        const u64t* s1 = slot + 4096;
        const u64t want64 = ((u64t)(unsigned)s << 48) | ((u64t)(unsigned)s << 16);
        for (;;) {
          u64t bad = 0;
          #pragma unroll
          for (int e = 0; e < 64; ++e)
            if ((hr[e] ^ want64) & 0xFFFF0000FFFF0000ull) bad |= (1ull << e);
          if (!bad) break;
          if (++spins > 8000000u) break;
          #pragma unroll
          for (int e = 0; e < 64; ++e)
            if (bad & (1ull << e))
              hr[e] = ld_u64(s1 + h1base + (e >> 2) * 16 + (e & 3));
        }
        // strip tags -> 16 h1 B-frags in registers
        f16x8 hb1[16];
        #pragma unroll
        for (int f = 0; f < 16; ++f) {
          u32x4 t;
          t[0] = payload(hr[f * 4 + 0]); t[1] = payload(hr[f * 4 + 1]);
          t[2] = payload(hr[f * 4 + 2]); t[3] = payload(hr[f * 4 + 3]);
          hb1[f] = __builtin_bit_cast(f16x8, t);
        }
        #pragma unroll
        for (int f = 0; f < 16; ++f) {           // h1 half from registers
          f16x8 bf = hb1[f];
          if (f & 1) { a0o = mfma16(wA[0][16 + f], bf, a0o); a1o = mfma16(wA[1][16 + f], bf, a1o); }
          else       { a0e = mfma16(wA[0][16 + f], bf, a0e); a1e = mfma16(wA[1][16 + f], bf, a1e); }
        }
        #pragma unroll
        for (int f = 0; f < 16; ++f) {           // h0 half from LDS
          f16x8 bf = *(const f16x8*)(cur + rowb + f * 64);
          if (f & 1) { a0o = mfma16(wA[0][f], bf, a0o); a1o = mfma16(wA[1][f], bf, a1o); }
          else       { a0e = mfma16(wA[0][f], bf, a0e); a1e = mfma16(wA[1][f], bf, a1e); }
        }
      }
      f32x4 acc0 = a0e + a0o;
      f32x4 acc1 = a1e + a1o;
      {
        float ii = sigm(acc0[0] + bias[0][0]);
        float ff = sigm(acc0[1] + bias[0][1]);
        float gg = tanhx(acc0[2] + bias[0][2]);
        float oo = sigm(acc0[3] + bias[0][3]);
        cst0 = ff * cst0 + ii * gg;
        hv0 = oo * tanhx(cst0);                  // even unit hb+2k
      }
      {
        float ii = sigm(acc1[0] + bias[1][0]);
        float ff = sigm(acc1[1] + bias[1][1]);
        float gg = tanhx(acc1[2] + bias[1][2]);
        float oo = sigm(acc1[3] + bias[1][3]);
        cst1 = ff * cst1 + ii * gg;
        hv1 = oo * tanhx(cst1);                  // odd unit hb+2k+1
      }
    }
    const bool produce = layer ? true : (s < T_SEQ);   // L1 emits zeros at s=0
    if (produce) {
      u64t tag2 = ((u64t)(unsigned)(s + 1) << 16) | ((u64t)(unsigned)(s + 1) << 48);
      u64t e = (u64t)(unsigned)__builtin_bit_cast(unsigned short, (_Float16)hv0);
      u64t o = (u64t)(unsigned)__builtin_bit_cast(unsigned short, (_Float16)hv1);
      u64t* dst = (u64t*)(gbase + (s % 3) * SLOT_U32 + layer * 8192
                          + bcol * 512 + hb) + kgrp;
      st_u64(dst, e | (o << 32) | tag2);         // units hb+2k, hb+2k+1
    }
    // no trailing barrier: next step writes the OTHER LDS buffer
  }

  __syncthreads();                               // main-loop reads done

  // ---- FC epilogue: out = relu([h0_T; h1_T] @ fc_w^T + fc_b), [128][1024]
  {
    const int rt = wid >> 4, ct = wid & 15;      // 8 row-tiles x 16 col-tiles
    const int sg = rt & 3;
    const bool isH1 = (rt >= 4);
    // h0_T: step 1023 -> slot 0, tag 1024; h1_T: step 1024 -> slot 1, tag 1025
    const unsigned want = isH1 ? (unsigned)STEPS : (unsigned)(STEPS - 1);
    const int     slot  = isH1 ? 1 : 0;
    const u64t* src = (const u64t*)(ws + sg * GRP_U32 + slot * SLOT_U32
                                    + (isH1 ? 8192 : 0));
    u64t v[16];
    #pragma unroll
    for (int i = 0; i < 16; ++i) v[i] = ld_u64(src + tid + i * 256);
    for (;;) {
      unsigned bad = 0;
      #pragma unroll
      for (int i = 0; i < 16; ++i) {
        unsigned lo = (unsigned)v[i], hi = (unsigned)(v[i] >> 32);
        if (((lo >> 16) ^ want) | ((hi >> 16) ^ want)) bad |= (1u << i);
      }
      if (!bad) break;
      if (++spins > 8000000u) break;
      #pragma unroll
      for (int i = 0; i < 16; ++i)
        if (bad & (1u << i)) v[i] = ld_u64(src + tid + i * 256);
    }
    #pragma unroll
    for (int i = 0; i < 16; ++i) {
      int j = tid + i * 256;                     // [16 batch][256 pairs]
      sH[0][(j >> 8) * 260 + (j & 255)] = payload(v[i]);
    }
    __syncthreads();
    const int col = ct * 64 + wv * 16 + bcol;
    f32x4 a0 = {0,0,0,0}, a1 = {0,0,0,0};
    #pragma unroll
    for (int f = 0; f < 16; ++f) {               // K = 512
      f16x8 af = *(const f16x8*)((const char*)sH[0] + rowb + f * 64);
      f16x8 bf = cvt8(fcw + (size_t)col * H + f * 32 + kgrp * 8);
      if (f & 1) a1 = mfma16(af, bf, a1); else a0 = mfma16(af, bf, a0);
    }
    f32x4 a = a0 + a1;
    const float fb = fcb[col];
    #pragma unroll
    for (int rr = 0; rr < 4; ++rr) {
      int row = rt * 16 + kgrp * 4 + rr;
      float v2 = a[rr] + fb;
      out[(size_t)row * 1024 + col] = v2 > 0.f ? v2 : 0.f;
    }
  }
}

extern "C" void kernel_launch(void* const* d_in, const int* in_sizes, int n_in,
                              void* d_out, int out_size, void* d_ws, size_t ws_size,
                              hipStream_t stream) {
  const float* x    = (const float*)d_in[0];
  const float* Wih0 = (const float*)d_in[1];
  const float* Whh0 = (const float*)d_in[2];
  const float* bih0 = (const float*)d_in[3];
  const float* bhh0 = (const float*)d_in[4];
  const float* Wih1 = (const float*)d_in[5];
  const float* Whh1 = (const float*)d_in[6];
  const float* bih1 = (const float*)d_in[7];
  const float* bhh1 = (const float*)d_in[8];
  const float* fcw  = (const float*)d_in[9];
  const float* fcb  = (const float*)d_in[10];
  (void)in_sizes; (void)n_in; (void)out_size; (void)ws_size;

  // zero tag space every call (tag 0 never matches any wanted tag >= 1)
  hipMemsetAsync(d_ws, 0, WS_BYTES, stream);
  lstm_fused<<<dim3(128), dim3(256), 0, stream>>>(
      x, Wih0, Whh0, bih0, bhh0, Wih1, Whh1, bih1, bhh1, fcw, fcb,
      (float*)d_out, (unsigned*)d_ws);
}

// Round 18
// 4017.168 us; speedup vs baseline: 2.6936x; 2.6936x over previous
//
#include <hip/hip_runtime.h>

// ---------------------------------------------------------------------------
// Persistent fused 2-layer LSTM + FC for MI355X — v14 FINAL (4026 us).
// Session summary (16 experiments):
//  v1 7646 -> v2 tagged-ring 4995 -> v6 fat-waves 4220 -> v13 chain-opts
//  4028 -> v14 4026. Falsified: LLC-bandwidth model (v11: traffic halved,
//  zero gain), sync-domain decoupling (v7), slot width (v9), batch-issue
//  (v10: early reads = stale = wasted re-reads), sentinel gating (v3),
//  MFMA dep-latency (v14 split: neutral), h1 direct-to-reg (v15: 128 extra
//  VGPRs can't fit beside 256 weight VGPRs -> spill, 10821 us).
//  Toolchain rules learned: 512-thr WGs cap at 128 VGPR (spill); 256-thr
//  WGs reach ~232 without spill; hr[64]-class register arrays spill at 256.
// Floor analysis: step = 3.93 us = serial chain {h0-drain RTT + retry +
//  [repack0 || h1 RTT] + retry1 + repack1 + barrier + MFMA+gates + store
//  visibility tail} x 1025 dependent steps. HBM 4.4%, MfmaUtil 4.3% —
//  a latency floor, not a roofline.
// Structure: 128 WGs x 256 thr (4 waves), 4 groups x 32 WGs, 1 WG/CU.
//  wv0/wv1 = L0 (8 units, K=576), wv2/wv3 = L1 (8 units, K=1024). Weights
//  resident in VGPRs (220). h: u32 = fp16|(tag<<16), 3-slot agent-scope
//  ring, speculative bulk read + per-word retry, u64 paired stores,
//  pass-1-under-RTT repack, double-buffered LDS staging, 1 barrier/step.
// ---------------------------------------------------------------------------

#define H      512
#define T_SEQ  1024
#define DIN    64
#define STEPS  1025

#define SLOT_U32 16384           // [2 layers][16 batch][512 units] tagged u32
#define GRP_U32  49152           // 3 slots
#define WS_BYTES (4 * GRP_U32 * 4)

typedef _Float16 f16x8 __attribute__((ext_vector_type(8)));
typedef float    f32x4 __attribute__((ext_vector_type(4)));
typedef unsigned long long u64t;

__device__ __forceinline__ u64t ld_u64(const u64t* p) {
  return __hip_atomic_load((u64t*)p, __ATOMIC_RELAXED, __HIP_MEMORY_SCOPE_AGENT);
}
__device__ __forceinline__ void st_u64(u64t* p, u64t v) {
  __hip_atomic_store(p, v, __ATOMIC_RELAXED, __HIP_MEMORY_SCOPE_AGENT);
}
__device__ __forceinline__ f16x8 pk8(float4 a, float4 b) {
  f16x8 r;
  r[0] = (_Float16)a.x; r[1] = (_Float16)a.y; r[2] = (_Float16)a.z; r[3] = (_Float16)a.w;
  r[4] = (_Float16)b.x; r[5] = (_Float16)b.y; r[6] = (_Float16)b.z; r[7] = (_Float16)b.w;
  return r;
}
__device__ __forceinline__ f16x8 cvt8(const float* p) {
  return pk8(*(const float4*)p, *(const float4*)(p + 4));
}
__device__ __forceinline__ f32x4 mfma16(f16x8 a, f16x8 b, f32x4 c) {
  return __builtin_amdgcn_mfma_f32_16x16x32_f16(a, b, c, 0, 0, 0);
}
__device__ __forceinline__ float rcpf_(float x) {
#if __has_builtin(__builtin_amdgcn_rcpf)
  return __builtin_amdgcn_rcpf(x);
#else
  return 1.0f / x;
#endif
}
__device__ __forceinline__ float sigm(float x) {
  x = fminf(fmaxf(x, -30.f), 30.f);
  return rcpf_(1.f + __expf(-x));
}
__device__ __forceinline__ float tanhx(float x) {
  x = fminf(fmaxf(x, -15.f), 15.f);
  float e = __expf(2.f * x);
  return (e - 1.f) * rcpf_(e + 1.f);
}
__device__ __forceinline__ unsigned payload(u64t v) {
  return ((unsigned)v & 0xffffu) | ((unsigned)(v >> 32) << 16);
}

__global__ __launch_bounds__(256, 1)
void lstm_fused(const float* __restrict__ x,
                const float* __restrict__ Wih0, const float* __restrict__ Whh0,
                const float* __restrict__ bih0, const float* __restrict__ bhh0,
                const float* __restrict__ Wih1, const float* __restrict__ Whh1,
                const float* __restrict__ bih1, const float* __restrict__ bhh1,
                const float* __restrict__ fcw,  const float* __restrict__ fcb,
                float* __restrict__ out, unsigned* __restrict__ ws)
{
  // double-buffered staged h: [buf][2 layers][16 batch][260 u32]
  __shared__ unsigned sH[2][8320];

  const int tid  = threadIdx.x;
  const int wid  = blockIdx.x;
  const int g    = wid >> 5;           // batch group 0..3
  const int w    = wid & 31;           // WG within group
  const int wv   = tid >> 6;           // wave 0..3
  const int lane = tid & 63;
  const int bcol = lane & 15;          // MFMA N col = batch-in-group
  const int kgrp = lane >> 4;
  const int layer = wv >> 1;
  const int hb    = w * 16 + (wv & 1) * 8;   // 8 units of this wave

  unsigned* gbase = ws + g * GRP_U32;

  // ---- resident weights: 2 M-tiles = even units (hb+2k) / odd (hb+2k+1)
  //      (pairing -> one u64 h-store per lane).
  //      M rows gate-interleaved: row m -> gate m&3, unit hb + 2*(m>>2)(+1).
  const int src_m = lane & 15;
  const int gr0 = (src_m & 3) * H + hb + 2 * (src_m >> 2);  // even-unit row
  const int gr1 = gr0 + 1;                                  // odd-unit row
  f16x8 wA[2][32];
  if (layer == 0) {                    // K = 64(x) + 512(h0): frags 0..17
    #pragma unroll
    for (int f = 0; f < 18; ++f) {
      const float *p0, *p1;
      if (f < 2) {
        p0 = Wih0 + (size_t)gr0 * DIN + f * 32 + kgrp * 8;
        p1 = Wih0 + (size_t)gr1 * DIN + f * 32 + kgrp * 8;
      } else {
        p0 = Whh0 + (size_t)gr0 * H + (f - 2) * 32 + kgrp * 8;
        p1 = Whh0 + (size_t)gr1 * H + (f - 2) * 32 + kgrp * 8;
      }
      wA[0][f] = cvt8(p0); wA[1][f] = cvt8(p1);
    }
  } else {                             // K = 512(h0) + 512(h1): frags 0..31
    #pragma unroll
    for (int f = 0; f < 16; ++f) {
      int col = f * 32 + kgrp * 8;
      wA[0][f] = cvt8(Wih1 + (size_t)gr0 * H + col);
      wA[1][f] = cvt8(Wih1 + (size_t)gr1 * H + col);
    }
    #pragma unroll
    for (int f = 16; f < 32; ++f) {
      int col = (f - 16) * 32 + kgrp * 8;
      wA[0][f] = cvt8(Whh1 + (size_t)gr0 * H + col);
      wA[1][f] = cvt8(Whh1 + (size_t)gr1 * H + col);
    }
  }
  float bias[2][4];
  {
    const float* bi = layer ? bih1 : bih0;
    const float* bh = layer ? bhh1 : bhh0;
    const int u0 = hb + 2 * kgrp, u1 = u0 + 1;
    #pragma unroll
    for (int rr = 0; rr < 4; ++rr) {
      bias[0][rr] = bi[rr * H + u0] + bh[rr * H + u0];
      bias[1][rr] = bi[rr * H + u1] + bh[rr * H + u1];
    }
  }

  // zero both staging buffers once (step 0 reads zeros as h_{-1})
  for (int i = tid; i < 2 * 8320; i += 256) ((unsigned*)sH)[i] = 0;
  __syncthreads();

  float cst0 = 0.f, cst1 = 0.f;
  unsigned spins = 0;                  // cumulative guard (normal use ~1e5)
  const int rowb = bcol * 1040 + kgrp * 16;   // byte offset of B-frag row

  for (int s = 0; s < STEPS; ++s) {
    // x prefetch for L0 waves (frags 0,1)
    float4 xr0 = {0,0,0,0}, xr1 = xr0, xr2 = xr0, xr3 = xr0;
    if (layer == 0) {
      int t = (s < T_SEQ) ? s : (T_SEQ - 1);
      const float* xp = x + ((size_t)((g * 16 + bcol) * T_SEQ + t)) * DIN + kgrp * 8;
      xr0 = *(const float4*)xp;        xr1 = *(const float4*)(xp + 4);
      xr2 = *(const float4*)(xp + 32); xr3 = *(const float4*)(xp + 36);
    }
    // stage tag-s data from slot (s-1)%3 into buf s&1:
    // drain h0 -> ISSUE h1 loads -> repack h0 (hidden under h1 RTT) ->
    // drain h1 -> repack h1.  (h1's delayed issue is load-bearing — v10.)
    if (s > 0) {
      const u64t* src = (const u64t*)(gbase + ((s - 1) % 3) * SLOT_U32);
      const unsigned want = (unsigned)s;
      unsigned* dstbuf = sH[s & 1];
      u64t v0[16], v1[16];
      #pragma unroll
      for (int i = 0; i < 16; ++i) v0[i] = ld_u64(src + tid + i * 256);
      for (;;) {                                 // verify pass 0 (h0 region)
        unsigned bad = 0;
        #pragma unroll
        for (int i = 0; i < 16; ++i) {
          unsigned lo = (unsigned)v0[i], hi = (unsigned)(v0[i] >> 32);
          if (((lo >> 16) ^ want) | ((hi >> 16) ^ want)) bad |= (1u << i);
        }
        if (!bad) break;
        if (++spins > 8000000u) break;           // bounded anti-hang guard
        #pragma unroll
        for (int i = 0; i < 16; ++i)
          if (bad & (1u << i)) v0[i] = ld_u64(src + tid + i * 256);
      }
      #pragma unroll
      for (int i = 0; i < 16; ++i)               // issue pass 1 (h1 region)
        v1[i] = ld_u64(src + tid + (16 + i) * 256);
      #pragma unroll
      for (int i = 0; i < 16; ++i) {             // repack pass 0 under h1 RTT
        int j = tid + i * 256;                   // [2][16][256] u64 index
        dstbuf[(j >> 12) * 4160 + ((j >> 8) & 15) * 260 + (j & 255)] = payload(v0[i]);
      }
      for (;;) {                                 // verify pass 1
        unsigned bad = 0;
        #pragma unroll
        for (int i = 0; i < 16; ++i) {
          unsigned lo = (unsigned)v1[i], hi = (unsigned)(v1[i] >> 32);
          if (((lo >> 16) ^ want) | ((hi >> 16) ^ want)) bad |= (1u << i);
        }
        if (!bad) break;
        if (++spins > 8000000u) break;
        #pragma unroll
        for (int i = 0; i < 16; ++i)
          if (bad & (1u << i)) v1[i] = ld_u64(src + tid + (16 + i) * 256);
      }
      #pragma unroll
      for (int i = 0; i < 16; ++i) {             // repack pass 1
        int j = tid + (16 + i) * 256;
        dstbuf[(j >> 12) * 4160 + ((j >> 8) & 15) * 260 + (j & 255)] = payload(v1[i]);
      }
    }
    __syncthreads();                             // staged; WAR handled by dbuf

    const bool act = layer ? (s > 0) : (s < T_SEQ);
    float hv0 = 0.f, hv1 = 0.f;
    if (act) {
      // 4 independent accumulator chains (even/odd frags x 2 tiles)
      f32x4 a0e = {0,0,0,0}, a0o = {0,0,0,0};
      f32x4 a1e = {0,0,0,0}, a1o = {0,0,0,0};
      const char* cur = (const char*)sH[s & 1];
      if (layer == 0) {
        f16x8 b0 = pk8(xr0, xr1);
        a0e = mfma16(wA[0][0], b0, a0e); a1e = mfma16(wA[1][0], b0, a1e);
        f16x8 b1 = pk8(xr2, xr3);
        a0o = mfma16(wA[0][1], b1, a0o); a1o = mfma16(wA[1][1], b1, a1o);
        #pragma unroll
        for (int f = 2; f < 18; ++f) {
          f16x8 bf = *(const f16x8*)(cur + rowb + (f - 2) * 64);
          if (f & 1) { a0o = mfma16(wA[0][f], bf, a0o); a1o = mfma16(wA[1][f], bf, a1o); }
          else       { a0e = mfma16(wA[0][f], bf, a0e); a1e = mfma16(wA[1][f], bf, a1e); }
        }
      } else {
        #pragma unroll
        for (int f = 0; f < 16; ++f) {
          f16x8 bf = *(const f16x8*)(cur + rowb + f * 64);
          if (f & 1) { a0o = mfma16(wA[0][f], bf, a0o); a1o = mfma16(wA[1][f], bf, a1o); }
          else       { a0e = mfma16(wA[0][f], bf, a0e); a1e = mfma16(wA[1][f], bf, a1e); }
        }
        #pragma unroll
        for (int f = 16; f < 32; ++f) {
          f16x8 bf = *(const f16x8*)(cur + 16640 + rowb + (f - 16) * 64);
          if (f & 1) { a0o = mfma16(wA[0][f], bf, a0o); a1o = mfma16(wA[1][f], bf, a1o); }
          else       { a0e = mfma16(wA[0][f], bf, a0e); a1e = mfma16(wA[1][f], bf, a1e); }
        }
      }
      f32x4 acc0 = a0e + a0o;
      f32x4 acc1 = a1e + a1o;
      {
        float ii = sigm(acc0[0] + bias[0][0]);
        float ff = sigm(acc0[1] + bias[0][1]);
        float gg = tanhx(acc0[2] + bias[0][2]);
        float oo = sigm(acc0[3] + bias[0][3]);
        cst0 = ff * cst0 + ii * gg;
        hv0 = oo * tanhx(cst0);                  // even unit hb+2k
      }
      {
        float ii = sigm(acc1[0] + bias[1][0]);
        float ff = sigm(acc1[1] + bias[1][1]);
        float gg = tanhx(acc1[2] + bias[1][2]);
        float oo = sigm(acc1[3] + bias[1][3]);
        cst1 = ff * cst1 + ii * gg;
        hv1 = oo * tanhx(cst1);                  // odd unit hb+2k+1
      }
    }
    const bool produce = layer ? true : (s < T_SEQ);   // L1 emits zeros at s=0
    if (produce) {
      u64t tag2 = ((u64t)(unsigned)(s + 1) << 16) | ((u64t)(unsigned)(s + 1) << 48);
      u64t e = (u64t)(unsigned)__builtin_bit_cast(unsigned short, (_Float16)hv0);
      u64t o = (u64t)(unsigned)__builtin_bit_cast(unsigned short, (_Float16)hv1);
      u64t* dst = (u64t*)(gbase + (s % 3) * SLOT_U32 + layer * 8192
                          + bcol * 512 + hb) + kgrp;
      st_u64(dst, e | (o << 32) | tag2);         // units hb+2k, hb+2k+1
    }
    // no trailing barrier: next step writes the OTHER LDS buffer
  }

  __syncthreads();                               // main-loop reads done

  // ---- FC epilogue: out = relu([h0_T; h1_T] @ fc_w^T + fc_b), [128][1024]
  {
    const int rt = wid >> 4, ct = wid & 15;      // 8 row-tiles x 16 col-tiles
    const int sg = rt & 3;
    const bool isH1 = (rt >= 4);
    // h0_T: step 1023 -> slot 0, tag 1024; h1_T: step 1024 -> slot 1, tag 1025
    const unsigned want = isH1 ? (unsigned)STEPS : (unsigned)(STEPS - 1);
    const int     slot  = isH1 ? 1 : 0;
    const u64t* src = (const u64t*)(ws + sg * GRP_U32 + slot * SLOT_U32
                                    + (isH1 ? 8192 : 0));
    u64t v[16];
    #pragma unroll
    for (int i = 0; i < 16; ++i) v[i] = ld_u64(src + tid + i * 256);
    for (;;) {
      unsigned bad = 0;
      #pragma unroll
      for (int i = 0; i < 16; ++i) {
        unsigned lo = (unsigned)v[i], hi = (unsigned)(v[i] >> 32);
        if (((lo >> 16) ^ want) | ((hi >> 16) ^ want)) bad |= (1u << i);
      }
      if (!bad) break;
      if (++spins > 8000000u) break;
      #pragma unroll
      for (int i = 0; i < 16; ++i)
        if (bad & (1u << i)) v[i] = ld_u64(src + tid + i * 256);
    }
    #pragma unroll
    for (int i = 0; i < 16; ++i) {
      int j = tid + i * 256;                     // [16 batch][256 pairs]
      sH[0][(j >> 8) * 260 + (j & 255)] = payload(v[i]);
    }
    __syncthreads();
    const int col = ct * 64 + wv * 16 + bcol;
    f32x4 a0 = {0,0,0,0}, a1 = {0,0,0,0};
    #pragma unroll
    for (int f = 0; f < 16; ++f) {               // K = 512
      f16x8 af = *(const f16x8*)((const char*)sH[0] + rowb + f * 64);
      f16x8 bf = cvt8(fcw + (size_t)col * H + f * 32 + kgrp * 8);
      if (f & 1) a1 = mfma16(af, bf, a1); else a0 = mfma16(af, bf, a0);
    }
    f32x4 a = a0 + a1;
    const float fb = fcb[col];
    #pragma unroll
    for (int rr = 0; rr < 4; ++rr) {
      int row = rt * 16 + kgrp * 4 + rr;
      float v2 = a[rr] + fb;
      out[(size_t)row * 1024 + col] = v2 > 0.f ? v2 : 0.f;
    }
  }
}

extern "C" void kernel_launch(void* const* d_in, const int* in_sizes, int n_in,
                              void* d_out, int out_size, void* d_ws, size_t ws_size,
                              hipStream_t stream) {
  const float* x    = (const float*)d_in[0];
  const float* Wih0 = (const float*)d_in[1];
  const float* Whh0 = (const float*)d_in[2];
  const float* bih0 = (const float*)d_in[3];
  const float* bhh0 = (const float*)d_in[4];
  const float* Wih1 = (const float*)d_in[5];
  const float* Whh1 = (const float*)d_in[6];
  const float* bih1 = (const float*)d_in[7];
  const float* bhh1 = (const float*)d_in[8];
  const float* fcw  = (const float*)d_in[9];
  const float* fcb  = (const float*)d_in[10];
  (void)in_sizes; (void)n_in; (void)out_size; (void)ws_size;

  // zero tag space every call (tag 0 never matches any wanted tag >= 1)
  hipMemsetAsync(d_ws, 0, WS_BYTES, stream);
  lstm_fused<<<dim3(128), dim3(256), 0, stream>>>(
      x, Wih0, Whh0, bih0, bhh0, Wih1, Whh1, bih1, bhh1, fcw, fcb,
      (float*)d_out, (unsigned*)d_ws);
}